// Round 15
// baseline (469.289 us; speedup 1.0000x reference)
//
#include <hip/hip_runtime.h>

#define AB 513
#define TD 263169   // 513*513

typedef float f4 __attribute__((ext_vector_type(4)));
typedef float f32x4 __attribute__((ext_vector_type(4)));
typedef short bf16x8 __attribute__((ext_vector_type(8)));
typedef int i32x4 __attribute__((ext_vector_type(4)));

// ---------------------------------------------------------------------------
// Kernel 1a: pool over S. 320 blocks: 0..191 vision (bt, d-chunk of 256),
// 192..319 audio. Thread = one d; fully coalesced.
// ---------------------------------------------------------------------------
__global__ __launch_bounds__(256) void pool_kernel(
    const float* __restrict__ vx, const float* __restrict__ ax,
    float* __restrict__ pvT, float* __restrict__ paT)
{
    int b = blockIdx.x;
    const float* x; float* pT; int D, bt, dc;
    if (b < 192) { x = vx; pT = pvT; D = 768; bt = b / 3; dc = b % 3; }
    else { b -= 192; x = ax; pT = paT; D = 512; bt = b >> 1; dc = b & 1; }
    const int d = dc * 256 + threadIdx.x;
    const float* xp = x + (size_t)bt * 64 * D + d;
    float s0 = 0.f, s1 = 0.f, s2 = 0.f, s3 = 0.f;
    #pragma unroll 4
    for (int ss = 0; ss < 64; ss += 4) {
        s0 += xp[(size_t)ss * D];
        s1 += xp[(size_t)(ss + 1) * D];
        s2 += xp[(size_t)(ss + 2) * D];
        s3 += xp[(size_t)(ss + 3) * D];
    }
    pT[d * 64 + bt] = ((s0 + s1) + (s2 + s3)) * 0.015625f;
}

// ---------------------------------------------------------------------------
// Kernel 1b: layer1, weight-stationary. Block = 8-h tile; wave = h row.
// ---------------------------------------------------------------------------
__global__ __launch_bounds__(512) void mlp1_kernel(
    const float* __restrict__ pvT, const float* __restrict__ paT,
    const float* __restrict__ vw1, const float* __restrict__ vb1,
    const float* __restrict__ aw1, const float* __restrict__ ab1,
    float* __restrict__ h1vT, float* __restrict__ h1aT)
{
    const int isA = (blockIdx.x >= 64);
    const int D = isA ? 512 : 768;
    const float* pT = isA ? paT : pvT;
    const float* w1 = isA ? aw1 : vw1;
    const float* b1 = isA ? ab1 : vb1;
    float* h1T = isA ? h1aT : h1vT;
    const int tid = threadIdx.x, lane = tid & 63, w = tid >> 6;
    const int h = (blockIdx.x & 63) * 8 + w;
    const float* wr = w1 + (size_t)h * D;

    float a0 = 0.f, a1 = 0.f, a2 = 0.f, a3 = 0.f;
    for (int d = 0; d < D; d += 16) {
        const f4 w0 = *(const f4*)(wr + d);
        const f4 w1v = *(const f4*)(wr + d + 4);
        const f4 w2v = *(const f4*)(wr + d + 8);
        const f4 w3v = *(const f4*)(wr + d + 12);
        #pragma unroll
        for (int q = 0; q < 4; ++q) {
            a0 = fmaf(w0[q],  pT[(d + q) * 64 + lane], a0);
            a1 = fmaf(w1v[q], pT[(d + 4 + q) * 64 + lane], a1);
            a2 = fmaf(w2v[q], pT[(d + 8 + q) * 64 + lane], a2);
            a3 = fmaf(w3v[q], pT[(d + 12 + q) * 64 + lane], a3);
        }
    }
    h1T[h * 64 + lane] = fmaxf((a0 + a1) + (a2 + a3) + b1[h], 0.f);
}

// ---------------------------------------------------------------------------
// Kernel 1c: layer2 (no relu) + trailing ones row.
// ---------------------------------------------------------------------------
__global__ __launch_bounds__(512) void mlp2_kernel(
    const float* __restrict__ h1vT, const float* __restrict__ h1aT,
    const float* __restrict__ vw2, const float* __restrict__ vb2,
    const float* __restrict__ aw2, const float* __restrict__ ab2,
    float* __restrict__ aTout, float* __restrict__ bTout)
{
    const int isA = (blockIdx.x >= 64);
    const float* hT = isA ? h1aT : h1vT;
    const float* w2 = isA ? aw2 : vw2;
    const float* b2 = isA ? ab2 : vb2;
    float* outT = isA ? bTout : aTout;
    const int tid = threadIdx.x, lane = tid & 63, w = tid >> 6;
    const int h = (blockIdx.x & 63) * 8 + w;
    const float* wr = w2 + (size_t)h * 512;

    float a0 = 0.f, a1 = 0.f, a2 = 0.f, a3 = 0.f;
    for (int d = 0; d < 512; d += 16) {
        const f4 w0 = *(const f4*)(wr + d);
        const f4 w1v = *(const f4*)(wr + d + 4);
        const f4 w2v = *(const f4*)(wr + d + 8);
        const f4 w3v = *(const f4*)(wr + d + 12);
        #pragma unroll
        for (int q = 0; q < 4; ++q) {
            a0 = fmaf(w0[q],  hT[(d + q) * 64 + lane], a0);
            a1 = fmaf(w1v[q], hT[(d + 4 + q) * 64 + lane], a1);
            a2 = fmaf(w2v[q], hT[(d + 8 + q) * 64 + lane], a2);
            a3 = fmaf(w3v[q], hT[(d + 12 + q) * 64 + lane], a3);
        }
    }
    outT[h * 64 + lane] = (a0 + a1) + (a2 + a3) + b2[h];
    if ((blockIdx.x & 63) == 0 && tid < 64) outT[512 * 64 + tid] = 1.0f;
}

// ---------------------------------------------------------------------------
// Kernel 1d: split bT into 3 truncated-bf16 levels in MFMA B-fragment order.
// bF[((kt*4+nt)*3+lvl)*512 + l*8 + i] = lvl(b[e = kt*32+(l>>4)*8+i]
//                                            [bt = nt*16+(l&15)])
// ---------------------------------------------------------------------------
__global__ __launch_bounds__(256) void bprep_kernel(
    const float* __restrict__ bT,   // (513, 64)
    short* __restrict__ bF)
{
    const int t = blockIdx.x * 256 + threadIdx.x;  // [0, 12288)
    const int l = t & 63, frag = t >> 6;           // frag in [0, 192)
    const int kt = frag / 12, rem = frag % 12;
    const int nt = rem / 3, lvl = rem % 3;
    const int bt = nt * 16 + (l & 15);
    const int ebase = kt * 32 + ((l >> 4) << 3);
    #pragma unroll
    for (int i = 0; i < 8; ++i) {
        const float v = bT[(size_t)(ebase + i) * 64 + bt];
        const unsigned u = __float_as_uint(v);
        const float r1 = v - __uint_as_float(u & 0xFFFF0000u);
        const unsigned u1 = __float_as_uint(r1);
        const float r2 = r1 - __uint_as_float(u1 & 0xFFFF0000u);
        const unsigned u2 = __float_as_uint(r2);
        const unsigned sel = (lvl == 0) ? u : (lvl == 1) ? u1 : u2;
        bF[(size_t)frag * 512 + l * 8 + i] = (short)(sel >> 16);
    }
}

// ---------------------------------------------------------------------------
// Kernel 2: bilinear, FLIPPED contraction:
//   u[d,bt] = sum_e W[d,e] b[e,bt]   (MFMA: M=d(512), N=bt(64), K=e(512))
//   y[bt]   = sum_d a[d,bt] (u[d,bt] + W[d,512])   (epilogue VALU)
// W is the A-operand -> lane l needs A[m=l&15][k=(l>>4)*8+i] = 8 CONSECUTIVE
// floats of one W row: plain global->VGPR dwordx4 pairs. NO LDS, NO barriers
// in the main loop; waves fully autonomous. In-register 3-level bf16 split
// (verified 6-term scheme). B-fragments pre-split by bprep (L2/L3-hot,
// coalesced 16B/lane). Block = o (1024 blocks, 512 thr, 1 block/CU).
// Wave w owns m-tiles mtg = 4w..4w+3 (d-rows [64w, 64w+64)), all 4 nt.
// ---------------------------------------------------------------------------
__global__ __launch_bounds__(512, 1) void bilinear_kernel(
    const float* __restrict__ fw1,  // (1024, 263169)
    const float* __restrict__ fb1,  // (1024)
    const float* __restrict__ aT,   // (513, 64)
    const float* __restrict__ bT,   // (513, 64)
    const short* __restrict__ bF,   // B-fragments
    float* __restrict__ hbufT)      // (1024, 64)
{
    __shared__ float red[8][64];
    __shared__ float redB[8][64];

    const int tid = threadIdx.x;
    const int l = tid & 63, w = tid >> 6;
    const int o = blockIdx.x;
    const float* __restrict__ W = fw1 + (size_t)o * TD;
    const int ln = l & 15, lq = l >> 4;

    #define WLOAD(W0r, W1r, kt_)                                               \
        do {                                                                   \
            _Pragma("unroll")                                                  \
            for (int mt_ = 0; mt_ < 4; ++mt_) {                                \
                const float* p_ = W + (size_t)((w * 4 + mt_) * 16 + ln) * AB   \
                                    + (kt_) * 32 + lq * 8;                     \
                W0r[mt_] = *(const f4*)p_;                                     \
                W1r[mt_] = *(const f4*)(p_ + 4);                               \
            }                                                                  \
        } while (0)

    #define BLOAD(kt_)                                                         \
        do {                                                                   \
            _Pragma("unroll")                                                  \
            for (int nt_ = 0; nt_ < 4; ++nt_) {                                \
                const short* q_ = bF + (size_t)(((kt_) * 4 + nt_) * 3) * 512 + l * 8; \
                B1[nt_] = *(const bf16x8*)(q_);                                \
                B2[nt_] = *(const bf16x8*)(q_ + 512);                          \
                B3[nt_] = *(const bf16x8*)(q_ + 1024);                         \
            }                                                                  \
        } while (0)

    #define COMPUTE(W0r, W1r)                                                  \
        do {                                                                   \
            _Pragma("unroll")                                                  \
            for (int mt = 0; mt < 4; ++mt) {                                   \
                unsigned u0[8], u1[8], u2[8];                                  \
                _Pragma("unroll")                                              \
                for (int i = 0; i < 8; ++i) {                                  \
                    const float v = (i < 4) ? W0r[mt][i] : W1r[mt][i - 4];     \
                    u0[i] = __float_as_uint(v);                                \
                    const float r1 = v - __uint_as_float(u0[i] & 0xFFFF0000u); \
                    u1[i] = __float_as_uint(r1);                               \
                    const float r2 = r1 - __uint_as_float(u1[i] & 0xFFFF0000u);\
                    u2[i] = __float_as_uint(r2);                               \
                }                                                              \
                i32x4 p1, p2, p3;                                              \
                _Pragma("unroll")                                              \
                for (int j = 0; j < 4; ++j) {                                  \
                    p1[j] = (int)((u0[2 * j + 1] & 0xFFFF0000u) | (u0[2 * j] >> 16)); \
                    p2[j] = (int)((u1[2 * j + 1] & 0xFFFF0000u) | (u1[2 * j] >> 16)); \
                    p3[j] = (int)((u2[2 * j + 1] & 0xFFFF0000u) | (u2[2 * j] >> 16)); \
                }                                                              \
                const bf16x8 A1 = __builtin_bit_cast(bf16x8, p1);              \
                const bf16x8 A2 = __builtin_bit_cast(bf16x8, p2);              \
                const bf16x8 A3 = __builtin_bit_cast(bf16x8, p3);              \
                _Pragma("unroll")                                              \
                for (int nt = 0; nt < 4; ++nt) {                               \
                    acc[mt][nt] = __builtin_amdgcn_mfma_f32_16x16x32_bf16(A1, B1[nt], acc[mt][nt], 0, 0, 0); \
                    acc[mt][nt] = __builtin_amdgcn_mfma_f32_16x16x32_bf16(A1, B2[nt], acc[mt][nt], 0, 0, 0); \
                    acc[mt][nt] = __builtin_amdgcn_mfma_f32_16x16x32_bf16(A2, B1[nt], acc[mt][nt], 0, 0, 0); \
                    acc[mt][nt] = __builtin_amdgcn_mfma_f32_16x16x32_bf16(A2, B2[nt], acc[mt][nt], 0, 0, 0); \
                    acc[mt][nt] = __builtin_amdgcn_mfma_f32_16x16x32_bf16(A1, B3[nt], acc[mt][nt], 0, 0, 0); \
                    acc[mt][nt] = __builtin_amdgcn_mfma_f32_16x16x32_bf16(A3, B1[nt], acc[mt][nt], 0, 0, 0); \
                }                                                              \
            }                                                                  \
        } while (0)

    f32x4 acc[4][4];
    #pragma unroll
    for (int mt = 0; mt < 4; ++mt)
        #pragma unroll
        for (int nt = 0; nt < 4; ++nt)
            acc[mt][nt] = (f32x4){0.f, 0.f, 0.f, 0.f};

    f4 Wa0[4], Wa1[4], Wb0[4], Wb1[4];
    bf16x8 B1[4], B2[4], B3[4];

    WLOAD(Wa0, Wa1, 0);

    #pragma unroll 1
    for (int it = 0; it < 7; ++it) {
        const int kt = 2 * it;
        WLOAD(Wb0, Wb1, kt + 1);   // prefetch next W (HBM latency)
        BLOAD(kt);                 // L2-hot B-frags
        COMPUTE(Wa0, Wa1);
        WLOAD(Wa0, Wa1, kt + 2);
        BLOAD(kt + 1);
        COMPUTE(Wb0, Wb1);
    }
    // kt = 14
    WLOAD(Wb0, Wb1, 15);
    BLOAD(14);
    COMPUTE(Wa0, Wa1);
    // kt = 15
    BLOAD(15);
    COMPUTE(Wb0, Wb1);

    // ---- epilogue ----
    // acc[mt][nt][r] = u[d = 64w + mt*16 + lq*4 + r][bt = nt*16 + ln]
    // y[nt] = sum over this lane's (mt, r) of a[d,bt] * (u + W[d,512])
    float y[4] = {0.f, 0.f, 0.f, 0.f};
    #pragma unroll
    for (int mt = 0; mt < 4; ++mt) {
        #pragma unroll
        for (int r = 0; r < 4; ++r) {
            const int d = 64 * w + mt * 16 + lq * 4 + r;
            const float wc = W[(size_t)d * AB + 512];   // e=512 col (b==1)
            #pragma unroll
            for (int nt = 0; nt < 4; ++nt) {
                const float av = aT[(size_t)d * 64 + nt * 16 + ln];
                y[nt] = fmaf(av, acc[mt][nt][r] + wc, y[nt]);
            }
        }
    }
    // fold over lq (lane bits 4,5)
    #pragma unroll
    for (int nt = 0; nt < 4; ++nt) {
        float v = y[nt];
        v += __shfl_xor(v, 16, 64);
        v += __shfl_xor(v, 32, 64);
        y[nt] = v;
    }
    if (lq == 0) {
        #pragma unroll
        for (int nt = 0; nt < 4; ++nt) red[w][nt * 16 + ln] = y[nt];
    }

    // d = 512 row (a == 1): sum_e W[512,e] b[e,bt]; wave covers e in
    // [64w, 64w+64); lane = bt
    {
        float s0 = 0.f, s1 = 0.f, s2 = 0.f, s3 = 0.f;
        const int e0 = 64 * w;
        #pragma unroll 4
        for (int k = 0; k < 64; k += 4) {
            s0 = fmaf(W[(size_t)512 * AB + e0 + k], bT[(size_t)(e0 + k) * 64 + l], s0);
            s1 = fmaf(W[(size_t)512 * AB + e0 + k + 1], bT[(size_t)(e0 + k + 1) * 64 + l], s1);
            s2 = fmaf(W[(size_t)512 * AB + e0 + k + 2], bT[(size_t)(e0 + k + 2) * 64 + l], s2);
            s3 = fmaf(W[(size_t)512 * AB + e0 + k + 3], bT[(size_t)(e0 + k + 3) * 64 + l], s3);
        }
        redB[w][l] = (s0 + s1) + (s2 + s3);
    }

    __syncthreads();

    if (w == 0) {
        float t2 = 0.f;
        #pragma unroll
        for (int k = 0; k < 8; ++k) t2 += red[k][l] + redB[k][l];
        t2 += W[(size_t)512 * AB + 512] + fb1[o];  // corner (a=b=1) + bias
        hbufT[(size_t)o * 64 + l] = fmaxf(t2, 0.f);
    }
    #undef WLOAD
    #undef BLOAD
    #undef COMPUTE
}

// ---------------------------------------------------------------------------
// Kernel 3a: fused[bt, f] = h[bt, :] @ fw2[f, :] + fb2[f].
// ---------------------------------------------------------------------------
__global__ __launch_bounds__(512) void fuse2_kernel(
    const float* __restrict__ hbufT,  // (1024, 64)
    const float* __restrict__ fw2,    // (512, 1024)
    const float* __restrict__ fb2,    // (512)
    float* __restrict__ fused)        // (64, 512)
{
    const int tid = threadIdx.x, lane = tid & 63, w = tid >> 6;
    #pragma unroll
    for (int k = 0; k < 2; ++k) {
        const int f = blockIdx.x * 16 + w * 2 + k;
        const float* wr = fw2 + (size_t)f * 1024;
        float a0 = 0.f, a1 = 0.f, a2 = 0.f, a3 = 0.f;
        for (int o = 0; o < 1024; o += 16) {
            const f4 w0 = *(const f4*)(wr + o);
            const f4 w1v = *(const f4*)(wr + o + 4);
            const f4 w2v = *(const f4*)(wr + o + 8);
            const f4 w3v = *(const f4*)(wr + o + 12);
            #pragma unroll
            for (int q = 0; q < 4; ++q) {
                a0 = fmaf(w0[q],  hbufT[(o + q) * 64 + lane], a0);
                a1 = fmaf(w1v[q], hbufT[(o + 4 + q) * 64 + lane], a1);
                a2 = fmaf(w2v[q], hbufT[(o + 8 + q) * 64 + lane], a2);
                a3 = fmaf(w3v[q], hbufT[(o + 12 + q) * 64 + lane], a3);
            }
        }
        fused[lane * 512 + f] = (a0 + a1) + (a2 + a3) + fb2[f];
    }
}

// ---------------------------------------------------------------------------
// Kernel 3b: LIF over time. 1024 independent (b, d) chains, T = 32.
// ---------------------------------------------------------------------------
__global__ __launch_bounds__(256) void lif_kernel(
    const float* __restrict__ fused,  // (2, 32, 512)
    float* __restrict__ out)          // (2, 32, 512)
{
    const int idx = blockIdx.x * 256 + threadIdx.x;
    if (idx >= 1024) return;
    const int b = idx >> 9, dd = idx & 511;
    float mem = 0.f;
    for (int t = 0; t < 32; ++t) {
        const size_t off = ((size_t)(b * 32 + t) * 512) + dd;
        mem = 0.9f * mem + fused[off];
        const float s = (mem >= 1.0f) ? 1.0f : 0.0f;
        out[off] = s;
        mem -= s;
    }
}

// ---------------------------------------------------------------------------
extern "C" void kernel_launch(void* const* d_in, const int* in_sizes, int n_in,
                              void* d_out, int out_size, void* d_ws, size_t ws_size,
                              hipStream_t stream) {
    const float* vision = (const float*)d_in[0];
    const float* audio  = (const float*)d_in[1];
    const float* vw1 = (const float*)d_in[2];
    const float* vb1 = (const float*)d_in[3];
    const float* vw2 = (const float*)d_in[4];
    const float* vb2 = (const float*)d_in[5];
    const float* aw1 = (const float*)d_in[6];
    const float* ab1 = (const float*)d_in[7];
    const float* aw2 = (const float*)d_in[8];
    const float* ab2 = (const float*)d_in[9];
    const float* fw1 = (const float*)d_in[10];
    const float* fb1 = (const float*)d_in[11];
    const float* fw2 = (const float*)d_in[12];
    const float* fb2 = (const float*)d_in[13];
    float* out = (float*)d_out;

    float* ws    = (float*)d_ws;
    float* pvT   = ws;                  // 768*64
    float* paT   = pvT + 768 * 64;      // 512*64
    float* h1vT  = paT + 512 * 64;      // 512*64
    float* h1aT  = h1vT + 512 * 64;     // 512*64
    float* aT    = h1aT + 512 * 64;     // 513*64
    float* bT    = aT + AB * 64;        // 513*64
    float* hbufT = bT + AB * 64;        // 1024*64
    float* fused = hbufT + 1024 * 64;   // 64*512
    short* bF    = (short*)(fused + 64 * 512);  // 192*512 = 98304 shorts

    pool_kernel<<<320, 256, 0, stream>>>(vision, audio, pvT, paT);
    mlp1_kernel<<<128, 512, 0, stream>>>(pvT, paT, vw1, vb1, aw1, ab1, h1vT, h1aT);
    mlp2_kernel<<<128, 512, 0, stream>>>(h1vT, h1aT, vw2, vb2, aw2, ab2, aT, bT);
    bprep_kernel<<<48, 256, 0, stream>>>(bT, bF);
    bilinear_kernel<<<1024, 512, 0, stream>>>(fw1, fb1, aT, bT, bF, hbufT);
    fuse2_kernel<<<32, 512, 0, stream>>>(hbufT, fw2, fb2, fused);
    lif_kernel<<<4, 256, 0, stream>>>(fused, out);
}

// Round 16
// 456.876 us; speedup vs baseline: 1.0272x; 1.0272x over previous
//
#include <hip/hip_runtime.h>

#define AB 513
#define TD 263169   // 513*513

typedef float f4 __attribute__((ext_vector_type(4)));
typedef float f32x4 __attribute__((ext_vector_type(4)));
typedef short bf16x8 __attribute__((ext_vector_type(8)));
typedef int i32x4 __attribute__((ext_vector_type(4)));
#define GAS __attribute__((address_space(1)))
#define LAS __attribute__((address_space(3)))

// ---------------------------------------------------------------------------
// Kernel 1a: pool over S. 320 blocks; thread = one d; fully coalesced.
// ---------------------------------------------------------------------------
__global__ __launch_bounds__(256) void pool_kernel(
    const float* __restrict__ vx, const float* __restrict__ ax,
    float* __restrict__ pvT, float* __restrict__ paT)
{
    int b = blockIdx.x;
    const float* x; float* pT; int D, bt, dc;
    if (b < 192) { x = vx; pT = pvT; D = 768; bt = b / 3; dc = b % 3; }
    else { b -= 192; x = ax; pT = paT; D = 512; bt = b >> 1; dc = b & 1; }
    const int d = dc * 256 + threadIdx.x;
    const float* xp = x + (size_t)bt * 64 * D + d;
    float s0 = 0.f, s1 = 0.f, s2 = 0.f, s3 = 0.f;
    #pragma unroll 4
    for (int ss = 0; ss < 64; ss += 4) {
        s0 += xp[(size_t)ss * D];
        s1 += xp[(size_t)(ss + 1) * D];
        s2 += xp[(size_t)(ss + 2) * D];
        s3 += xp[(size_t)(ss + 3) * D];
    }
    pT[d * 64 + bt] = ((s0 + s1) + (s2 + s3)) * 0.015625f;
}

// ---------------------------------------------------------------------------
// Kernel 1b: layer1, weight-stationary.
// ---------------------------------------------------------------------------
__global__ __launch_bounds__(512) void mlp1_kernel(
    const float* __restrict__ pvT, const float* __restrict__ paT,
    const float* __restrict__ vw1, const float* __restrict__ vb1,
    const float* __restrict__ aw1, const float* __restrict__ ab1,
    float* __restrict__ h1vT, float* __restrict__ h1aT)
{
    const int isA = (blockIdx.x >= 64);
    const int D = isA ? 512 : 768;
    const float* pT = isA ? paT : pvT;
    const float* w1 = isA ? aw1 : vw1;
    const float* b1 = isA ? ab1 : vb1;
    float* h1T = isA ? h1aT : h1vT;
    const int tid = threadIdx.x, lane = tid & 63, w = tid >> 6;
    const int h = (blockIdx.x & 63) * 8 + w;
    const float* wr = w1 + (size_t)h * D;

    float a0 = 0.f, a1 = 0.f, a2 = 0.f, a3 = 0.f;
    for (int d = 0; d < D; d += 16) {
        const f4 w0 = *(const f4*)(wr + d);
        const f4 w1v = *(const f4*)(wr + d + 4);
        const f4 w2v = *(const f4*)(wr + d + 8);
        const f4 w3v = *(const f4*)(wr + d + 12);
        #pragma unroll
        for (int q = 0; q < 4; ++q) {
            a0 = fmaf(w0[q],  pT[(d + q) * 64 + lane], a0);
            a1 = fmaf(w1v[q], pT[(d + 4 + q) * 64 + lane], a1);
            a2 = fmaf(w2v[q], pT[(d + 8 + q) * 64 + lane], a2);
            a3 = fmaf(w3v[q], pT[(d + 12 + q) * 64 + lane], a3);
        }
    }
    h1T[h * 64 + lane] = fmaxf((a0 + a1) + (a2 + a3) + b1[h], 0.f);
}

// ---------------------------------------------------------------------------
// Kernel 1c: layer2 (no relu) + trailing ones row.
// ---------------------------------------------------------------------------
__global__ __launch_bounds__(512) void mlp2_kernel(
    const float* __restrict__ h1vT, const float* __restrict__ h1aT,
    const float* __restrict__ vw2, const float* __restrict__ vb2,
    const float* __restrict__ aw2, const float* __restrict__ ab2,
    float* __restrict__ aTout, float* __restrict__ bTout)
{
    const int isA = (blockIdx.x >= 64);
    const float* hT = isA ? h1aT : h1vT;
    const float* w2 = isA ? aw2 : vw2;
    const float* b2 = isA ? ab2 : vb2;
    float* outT = isA ? bTout : aTout;
    const int tid = threadIdx.x, lane = tid & 63, w = tid >> 6;
    const int h = (blockIdx.x & 63) * 8 + w;
    const float* wr = w2 + (size_t)h * 512;

    float a0 = 0.f, a1 = 0.f, a2 = 0.f, a3 = 0.f;
    for (int d = 0; d < 512; d += 16) {
        const f4 w0 = *(const f4*)(wr + d);
        const f4 w1v = *(const f4*)(wr + d + 4);
        const f4 w2v = *(const f4*)(wr + d + 8);
        const f4 w3v = *(const f4*)(wr + d + 12);
        #pragma unroll
        for (int q = 0; q < 4; ++q) {
            a0 = fmaf(w0[q],  hT[(d + q) * 64 + lane], a0);
            a1 = fmaf(w1v[q], hT[(d + 4 + q) * 64 + lane], a1);
            a2 = fmaf(w2v[q], hT[(d + 8 + q) * 64 + lane], a2);
            a3 = fmaf(w3v[q], hT[(d + 12 + q) * 64 + lane], a3);
        }
    }
    outT[h * 64 + lane] = (a0 + a1) + (a2 + a3) + b2[h];
    if ((blockIdx.x & 63) == 0 && tid < 64) outT[512 * 64 + tid] = 1.0f;
}

// ---------------------------------------------------------------------------
// Kernel 1d: split aT into 3 truncated-bf16 levels, chunked layout:
// aFc[((kt*12 + mt*3 + lvl)*64 + l)*8 + i]
// ---------------------------------------------------------------------------
__global__ __launch_bounds__(256) void aprep_kernel(
    const float* __restrict__ aT,   // (513, 64)
    short* __restrict__ aFc)
{
    const int t = blockIdx.x * 256 + threadIdx.x;  // [0, 4096)
    const int l = t & 63, mt = (t >> 6) & 3, kt = t >> 8;
    const int m = mt * 16 + (l & 15);
    const int kbase = kt * 32 + ((l >> 4) << 3);
    const int cb = kt * 12 + mt * 3;
    #pragma unroll
    for (int i = 0; i < 8; ++i) {
        const float v = aT[(size_t)(kbase + i) * 64 + m];
        const unsigned u = __float_as_uint(v);
        const float r1 = v - __uint_as_float(u & 0xFFFF0000u);
        const unsigned u1 = __float_as_uint(r1);
        const float r2 = r1 - __uint_as_float(u1 & 0xFFFF0000u);
        const unsigned u2 = __float_as_uint(r2);
        aFc[((size_t)(cb + 0) * 64 + l) * 8 + i] = (short)(u >> 16);
        aFc[((size_t)(cb + 1) * 64 + l) * 8 + i] = (short)(u1 >> 16);
        aFc[((size_t)(cb + 2) * 64 + l) * 8 + i] = (short)(u2 >> 16);
    }
}

// ---------------------------------------------------------------------------
// Kernel 1e: aux[o][bt] = sum_{d<=512} a[d,bt] W[d,512] (a[512]=1, incl corner)
//                       + sum_{e<512} W[512,e] b[e,bt] + fb1[o]
// Moves all bilinear-epilogue global reads out of the streaming kernel.
// ---------------------------------------------------------------------------
__global__ __launch_bounds__(512) void aux_kernel(
    const float* __restrict__ fw1, const float* __restrict__ fb1,
    const float* __restrict__ aT, const float* __restrict__ bT,
    float* __restrict__ aux)    // (1024, 64)
{
    __shared__ float wc[513], wr[512], r8[8][64];
    const int o = blockIdx.x, tid = threadIdx.x;
    const int l = tid & 63, w = tid >> 6;
    const float* __restrict__ W = fw1 + (size_t)o * TD;
    wc[tid] = W[(size_t)tid * AB + 512];
    if (tid == 0) wc[512] = W[(size_t)512 * AB + 512];
    wr[tid] = W[(size_t)512 * AB + tid];
    __syncthreads();
    float s = 0.f;
    for (int i = w; i < 513; i += 8) {
        s = fmaf(wc[i], aT[(size_t)i * 64 + l], s);
        if (i < 512) s = fmaf(wr[i], bT[(size_t)i * 64 + l], s);
    }
    r8[w][l] = s;
    __syncthreads();
    if (w == 0) {
        float t = fb1[o];
        #pragma unroll
        for (int k = 0; k < 8; ++k) t += r8[k][l];
        aux[(size_t)o * 64 + l] = t;
    }
}

// ---------------------------------------------------------------------------
// Kernel 2: PERSISTENT bilinear via bf16-split MFMA (R14 dataflow, verified).
// 256 blocks x 4 o's each; the DMA ring streams CONTINUOUSLY across o's:
// 128 global epochs g (o = o0+g/32, kt=(g%32)>>1, eh=g&1), W-ring slot g%3,
// A-ring slot gk%3 (gk = g>>1). Uniform s_waitcnt vmcnt(6) per epoch (FIFO
// traced; dup-stages at the tail write identical bytes). Epilogues have ZERO
// global loads: b-scale f4s + aux preloaded to registers before the first
// stage; hbufT stores deferred past the final drain. No drains anywhere.
// ---------------------------------------------------------------------------
__global__ __launch_bounds__(512, 1) void bilinear_kernel(
    const float* __restrict__ fw1,  // (1024, 263169)
    const float* __restrict__ bT,   // (513, 64)
    const short* __restrict__ aFc,  // A-frag chunks
    const float* __restrict__ aux,  // (1024, 64)
    float* __restrict__ hbufT)      // (1024, 64)
{
    __shared__ float wring[3][8192];   // 96 KB
    __shared__ short aring[3][6144];   // 36 KB
    __shared__ float adump[256];       // 1 KB
    __shared__ float red[8][64];       // 2 KB

    const int tid = threadIdx.x;
    const int l = tid & 63, w = tid >> 6;
    const int o0 = blockIdx.x * 4;
    const int lq = l >> 4, ln = l & 15;

    #define SW(gg_)                                                            \
        do {                                                                   \
            const int G_ = (gg_);                                              \
            const int oo_ = o0 + (G_ >> 5);                                    \
            const int kq_ = (G_ >> 1) & 15, eh_ = G_ & 1, sl_ = G_ % 3;        \
            const float* base_ = fw1 + (size_t)oo_ * TD                        \
                + (size_t)(kq_ * 32) * AB + 256 * eh_ + l * 4;                 \
            _Pragma("unroll")                                                  \
            for (int rr_ = 0; rr_ < 4; ++rr_) {                                \
                const int r_ = w * 4 + rr_;                                    \
                __builtin_amdgcn_global_load_lds(                              \
                    (const GAS unsigned*)(const void*)(base_ + (size_t)r_ * AB), \
                    (LAS unsigned*)(void*)(&wring[sl_][r_ * 256]), 16, 0, 0);  \
            }                                                                  \
        } while (0)

    #define SA(gg_)                                                            \
        do {                                                                   \
            const int gk_ = (gg_);                                             \
            const int c_ = gk_ & 15, sl_ = gk_ % 3;                            \
            const int c0_ = (w < 4) ? (2 * w) : (4 + w);                       \
            const short* s0_ = aFc + ((size_t)c_ * 12 + c0_) * 512;            \
            __builtin_amdgcn_global_load_lds(                                  \
                (const GAS unsigned*)(const void*)(s0_ + l * 8),               \
                (LAS unsigned*)(void*)(&aring[sl_][c0_ * 512]), 16, 0, 0);     \
            if (w < 4) {                                                       \
                const int c1_ = 2 * w + 1;                                     \
                const short* s1_ = aFc + ((size_t)c_ * 12 + c1_) * 512;        \
                __builtin_amdgcn_global_load_lds(                              \
                    (const GAS unsigned*)(const void*)(s1_ + l * 8),           \
                    (LAS unsigned*)(void*)(&aring[sl_][c1_ * 512]), 16, 0, 0); \
            } else {                                                           \
                __builtin_amdgcn_global_load_lds(                              \
                    (const GAS unsigned*)(const void*)(aFc + (size_t)c_ * 12 * 512 + l * 2), \
                    (LAS unsigned*)(void*)(adump), 4, 0, 0);                   \
            }                                                                  \
        } while (0)

    #define LA(gg_)                                                            \
        do {                                                                   \
            const int sl_ = (gg_) % 3;                                         \
            _Pragma("unroll")                                                  \
            for (int mt_ = 0; mt_ < 4; ++mt_) {                                \
                A1[mt_] = *(const bf16x8*)&aring[sl_][(mt_ * 3 + 0) * 512 + l * 8]; \
                A2[mt_] = *(const bf16x8*)&aring[sl_][(mt_ * 3 + 1) * 512 + l * 8]; \
                A3[mt_] = *(const bf16x8*)&aring[sl_][(mt_ * 3 + 2) * 512 + l * 8]; \
            }                                                                  \
        } while (0)

    #define COMPUTE(gg_, EHC)                                                  \
        do {                                                                   \
            const float* __restrict__ wb_ = &wring[(gg_) % 3][0];              \
            _Pragma("unroll")                                                  \
            for (int ntl = 0; ntl < 2; ++ntl) {                                \
                const int col_ = 32 * w + 16 * ntl + ln;                       \
                unsigned u0[8], u1[8], u2[8];                                  \
                _Pragma("unroll")                                              \
                for (int i = 0; i < 8; ++i) {                                  \
                    const float v = wb_[(lq * 8 + i) * 256 + col_];            \
                    u0[i] = __float_as_uint(v);                                \
                    const float r1 = v - __uint_as_float(u0[i] & 0xFFFF0000u); \
                    u1[i] = __float_as_uint(r1);                               \
                    const float r2 = r1 - __uint_as_float(u1[i] & 0xFFFF0000u);\
                    u2[i] = __float_as_uint(r2);                               \
                }                                                              \
                i32x4 p1, p2, p3;                                              \
                _Pragma("unroll")                                              \
                for (int j = 0; j < 4; ++j) {                                  \
                    p1[j] = (int)((u0[2 * j + 1] & 0xFFFF0000u) | (u0[2 * j] >> 16)); \
                    p2[j] = (int)((u1[2 * j + 1] & 0xFFFF0000u) | (u1[2 * j] >> 16)); \
                    p3[j] = (int)((u2[2 * j + 1] & 0xFFFF0000u) | (u2[2 * j] >> 16)); \
                }                                                              \
                const bf16x8 B1 = __builtin_bit_cast(bf16x8, p1);              \
                const bf16x8 B2 = __builtin_bit_cast(bf16x8, p2);              \
                const bf16x8 B3 = __builtin_bit_cast(bf16x8, p3);              \
                _Pragma("unroll")                                              \
                for (int mt = 0; mt < 4; ++mt) {                               \
                    acc[mt][(EHC) * 2 + ntl] = __builtin_amdgcn_mfma_f32_16x16x32_bf16(A1[mt], B1, acc[mt][(EHC) * 2 + ntl], 0, 0, 0); \
                    acc[mt][(EHC) * 2 + ntl] = __builtin_amdgcn_mfma_f32_16x16x32_bf16(A1[mt], B2, acc[mt][(EHC) * 2 + ntl], 0, 0, 0); \
                    acc[mt][(EHC) * 2 + ntl] = __builtin_amdgcn_mfma_f32_16x16x32_bf16(A2[mt], B1, acc[mt][(EHC) * 2 + ntl], 0, 0, 0); \
                    acc[mt][(EHC) * 2 + ntl] = __builtin_amdgcn_mfma_f32_16x16x32_bf16(A2[mt], B2, acc[mt][(EHC) * 2 + ntl], 0, 0, 0); \
                    acc[mt][(EHC) * 2 + ntl] = __builtin_amdgcn_mfma_f32_16x16x32_bf16(A1[mt], B3, acc[mt][(EHC) * 2 + ntl], 0, 0, 0); \
                    acc[mt][(EHC) * 2 + ntl] = __builtin_amdgcn_mfma_f32_16x16x32_bf16(A3[mt], B1, acc[mt][(EHC) * 2 + ntl], 0, 0, 0); \
                }                                                              \
            }                                                                  \
        } while (0)

    #define EPI(jj_)                                                           \
        do {                                                                   \
            float ysum[4][4];                                                  \
            _Pragma("unroll")                                                  \
            for (int mt = 0; mt < 4; ++mt)                                     \
                _Pragma("unroll")                                              \
                for (int r = 0; r < 4; ++r) ysum[mt][r] = 0.f;                 \
            _Pragma("unroll")                                                  \
            for (int mt = 0; mt < 4; ++mt)                                     \
                _Pragma("unroll")                                              \
                for (int ntg = 0; ntg < 4; ++ntg)                              \
                    _Pragma("unroll")                                          \
                    for (int r = 0; r < 4; ++r)                                \
                        ysum[mt][r] = fmaf(acc[mt][ntg][r], bv[mt][ntg][r], ysum[mt][r]); \
            _Pragma("unroll")                                                  \
            for (int mt = 0; mt < 4; ++mt)                                     \
                _Pragma("unroll")                                              \
                for (int r = 0; r < 4; ++r) {                                  \
                    float v = ysum[mt][r];                                     \
                    v += __shfl_xor(v, 1, 64);                                 \
                    v += __shfl_xor(v, 2, 64);                                 \
                    v += __shfl_xor(v, 4, 64);                                 \
                    v += __shfl_xor(v, 8, 64);                                 \
                    ysum[mt][r] = v;                                           \
                }                                                              \
            if (ln == 0) {                                                     \
                _Pragma("unroll")                                              \
                for (int mt = 0; mt < 4; ++mt)                                 \
                    _Pragma("unroll")                                          \
                    for (int r = 0; r < 4; ++r)                                \
                        red[w][mt * 16 + lq * 4 + r] = ysum[mt][r];            \
            }                                                                  \
            asm volatile("s_waitcnt lgkmcnt(0)" ::: "memory");                 \
            __builtin_amdgcn_s_barrier();                                      \
            if (w == 0) {                                                      \
                float t2 = auxv[jj_];                                          \
                _Pragma("unroll")                                              \
                for (int k = 0; k < 8; ++k) t2 += red[k][l];                   \
                res[jj_] = fmaxf(t2, 0.f);                                     \
            }                                                                  \
            __builtin_amdgcn_s_barrier();                                      \
            _Pragma("unroll")                                                  \
            for (int mt = 0; mt < 4; ++mt)                                     \
                _Pragma("unroll")                                              \
                for (int ntg = 0; ntg < 4; ++ntg)                              \
                    acc[mt][ntg] = (f32x4){0.f, 0.f, 0.f, 0.f};                \
        } while (0)

    #define ODO(jj_)                                                           \
        do {                                                                   \
            _Pragma("unroll 1")                                                \
            for (int kt = 0; kt < 16; ++kt) {                                  \
                const int g = (jj_) * 32 + 2 * kt;                             \
                const int gk = (jj_) * 16 + kt;                                \
                asm volatile("s_waitcnt vmcnt(6)" ::: "memory");               \
                __builtin_amdgcn_s_barrier();                                  \
                LA(gk);                                                        \
                COMPUTE(g, 0);                                                 \
                __builtin_amdgcn_s_barrier();                                  \
                { const int t1 = (g + 2 > 127) ? 127 : g + 2; SW(t1); }        \
                { const int t2 = (gk + 2 > 63) ? 63 : gk + 2; SA(t2); }        \
                asm volatile("s_waitcnt vmcnt(6)" ::: "memory");               \
                __builtin_amdgcn_s_barrier();                                  \
                COMPUTE(g + 1, 1);                                             \
                __builtin_amdgcn_s_barrier();                                  \
                { const int t3 = (g + 3 > 127) ? 127 : g + 3; SW(t3); }        \
            }                                                                  \
            EPI(jj_);                                                          \
        } while (0)

    f32x4 acc[4][4];
    #pragma unroll
    for (int mt = 0; mt < 4; ++mt)
        #pragma unroll
        for (int ntg = 0; ntg < 4; ++ntg)
            acc[mt][ntg] = (f32x4){0.f, 0.f, 0.f, 0.f};
    bf16x8 A1[4], A2[4], A3[4];
    float res[4];

    // register preloads (epilogue then needs ZERO global loads)
    f4 bv[4][4];
    #pragma unroll
    for (int mt = 0; mt < 4; ++mt)
        #pragma unroll
        for (int ntg = 0; ntg < 4; ++ntg) {
            const int e = 256 * (ntg >> 1) + 32 * w + 16 * (ntg & 1) + ln;
            bv[mt][ntg] = *(const f4*)(bT + (size_t)e * 64 + mt * 16 + lq * 4);
        }
    float auxv[4];
    #pragma unroll
    for (int jj = 0; jj < 4; ++jj) auxv[jj] = aux[(size_t)(o0 + jj) * 64 + l];

    // prologue: [preloads | W(0):4 | A(0):2 | W(1):4 | A(1):2]
    SW(0); SA(0); SW(1); SA(1);

    ODO(0);
    ODO(1);
    ODO(2);
    ODO(3);

    asm volatile("s_waitcnt vmcnt(0)" ::: "memory");
    if (w == 0) {
        #pragma unroll
        for (int jj = 0; jj < 4; ++jj)
            hbufT[(size_t)(o0 + jj) * 64 + l] = res[jj];
    }
    #undef SW
    #undef SA
    #undef LA
    #undef COMPUTE
    #undef EPI
    #undef ODO
}

// ---------------------------------------------------------------------------
// Kernel 3a: fused[bt, f] = h[bt, :] @ fw2[f, :] + fb2[f].
// ---------------------------------------------------------------------------
__global__ __launch_bounds__(512) void fuse2_kernel(
    const float* __restrict__ hbufT,  // (1024, 64)
    const float* __restrict__ fw2,    // (512, 1024)
    const float* __restrict__ fb2,    // (512)
    float* __restrict__ fused)        // (64, 512)
{
    const int tid = threadIdx.x, lane = tid & 63, w = tid >> 6;
    #pragma unroll
    for (int k = 0; k < 2; ++k) {
        const int f = blockIdx.x * 16 + w * 2 + k;
        const float* wr = fw2 + (size_t)f * 1024;
        float a0 = 0.f, a1 = 0.f, a2 = 0.f, a3 = 0.f;
        for (int o = 0; o < 1024; o += 16) {
            const f4 w0 = *(const f4*)(wr + o);
            const f4 w1v = *(const f4*)(wr + o + 4);
            const f4 w2v = *(const f4*)(wr + o + 8);
            const f4 w3v = *(const f4*)(wr + o + 12);
            #pragma unroll
            for (int q = 0; q < 4; ++q) {
                a0 = fmaf(w0[q],  hbufT[(o + q) * 64 + lane], a0);
                a1 = fmaf(w1v[q], hbufT[(o + 4 + q) * 64 + lane], a1);
                a2 = fmaf(w2v[q], hbufT[(o + 8 + q) * 64 + lane], a2);
                a3 = fmaf(w3v[q], hbufT[(o + 12 + q) * 64 + lane], a3);
            }
        }
        fused[lane * 512 + f] = (a0 + a1) + (a2 + a3) + fb2[f];
    }
}

// ---------------------------------------------------------------------------
// Kernel 3b: LIF over time. 1024 independent (b, d) chains, T = 32.
// ---------------------------------------------------------------------------
__global__ __launch_bounds__(256) void lif_kernel(
    const float* __restrict__ fused,  // (2, 32, 512)
    float* __restrict__ out)          // (2, 32, 512)
{
    const int idx = blockIdx.x * 256 + threadIdx.x;
    if (idx >= 1024) return;
    const int b = idx >> 9, dd = idx & 511;
    float mem = 0.f;
    for (int t = 0; t < 32; ++t) {
        const size_t off = ((size_t)(b * 32 + t) * 512) + dd;
        mem = 0.9f * mem + fused[off];
        const float s = (mem >= 1.0f) ? 1.0f : 0.0f;
        out[off] = s;
        mem -= s;
    }
}

// ---------------------------------------------------------------------------
extern "C" void kernel_launch(void* const* d_in, const int* in_sizes, int n_in,
                              void* d_out, int out_size, void* d_ws, size_t ws_size,
                              hipStream_t stream) {
    const float* vision = (const float*)d_in[0];
    const float* audio  = (const float*)d_in[1];
    const float* vw1 = (const float*)d_in[2];
    const float* vb1 = (const float*)d_in[3];
    const float* vw2 = (const float*)d_in[4];
    const float* vb2 = (const float*)d_in[5];
    const float* aw1 = (const float*)d_in[6];
    const float* ab1 = (const float*)d_in[7];
    const float* aw2 = (const float*)d_in[8];
    const float* ab2 = (const float*)d_in[9];
    const float* fw1 = (const float*)d_in[10];
    const float* fb1 = (const float*)d_in[11];
    const float* fw2 = (const float*)d_in[12];
    const float* fb2 = (const float*)d_in[13];
    float* out = (float*)d_out;

    float* ws    = (float*)d_ws;
    float* pvT   = ws;                  // 768*64
    float* paT   = pvT + 768 * 64;      // 512*64
    float* h1vT  = paT + 512 * 64;      // 512*64
    float* h1aT  = h1vT + 512 * 64;     // 512*64
    float* aT    = h1aT + 512 * 64;     // 513*64
    float* bT    = aT + AB * 64;        // 513*64
    float* hbufT = bT + AB * 64;        // 1024*64
    float* fused = hbufT + 1024 * 64;   // 64*512
    short* aFc   = (short*)(fused + 64 * 512);  // 16*12*512 shorts
    float* aux   = (float*)(aFc + 98304);       // 1024*64

    pool_kernel<<<320, 256, 0, stream>>>(vision, audio, pvT, paT);
    mlp1_kernel<<<128, 512, 0, stream>>>(pvT, paT, vw1, vb1, aw1, ab1, h1vT, h1aT);
    mlp2_kernel<<<128, 512, 0, stream>>>(h1vT, h1aT, vw2, vb2, aw2, ab2, aT, bT);
    aprep_kernel<<<16, 256, 0, stream>>>(aT, aFc);
    aux_kernel<<<1024, 512, 0, stream>>>(fw1, fb1, aT, bT, aux);
    bilinear_kernel<<<256, 512, 0, stream>>>(fw1, bT, aFc, aux, hbufT);
    fuse2_kernel<<<32, 512, 0, stream>>>(hbufT, fw2, fb2, fused);
    lif_kernel<<<4, 256, 0, stream>>>(fused, out);
}